// Round 5
// baseline (520.189 us; speedup 1.0000x reference)
//
#include <hip/hip_runtime.h>
#include <math.h>

#define NS 4096
#define NF 512
#define NB 16
#define NC 10
#define HS 6144            // slots per column hash (lf 0.67), init-slot via umulhi
#define HEMPTY 0xFFFFFFFFu

// ws layout: int perm[16][4096] (256 KB), then int prefix[16][11]
#define PERM_BYTES (NB * NS * 4)

// ---------------- K0: counting-sort row indices by class (per b) ----------------
__global__ void sort_rows_kernel(const int* __restrict__ y,
                                 int* __restrict__ perm,
                                 int* __restrict__ prefix) {
    __shared__ int hist[NC], cur[NC], pfx[NC + 1];
    const int b = blockIdx.x, tid = threadIdx.x;
    if (tid < NC) hist[tid] = 0;
    __syncthreads();
    for (int s = tid; s < NS; s += 256) atomicAdd(&hist[y[b * NS + s]], 1);
    __syncthreads();
    if (tid == 0) {
        int acc = 0;
        for (int c = 0; c < NC; c++) { pfx[c] = acc; cur[c] = acc; acc += hist[c]; }
        pfx[NC] = acc;
    }
    __syncthreads();
    if (tid < NC + 1) prefix[b * (NC + 1) + tid] = pfx[tid];
    for (int s = tid; s < NS; s += 256) {
        const int pos = atomicAdd(&cur[y[b * NS + s]], 1);   // order within class irrelevant
        perm[b * NS + pos] = s;
    }
}

// ---------------- helpers ----------------
__device__ __forceinline__ float wred_add(float v) {
    #pragma unroll
    for (int off = 32; off > 0; off >>= 1) v += __shfl_down(v, off, 64);
    return v;
}
__device__ __forceinline__ float wred_max(float v) {
    #pragma unroll
    for (int off = 32; off > 0; off >>= 1) v = fmaxf(v, __shfl_down(v, off, 64));
    return v;
}
__device__ __forceinline__ void hash_insert(unsigned int* h, float x, int& u) {
    unsigned int pat = __float_as_uint(x);
    if (pat == 0x80000000u) pat = 0u;            // -0.0 == +0.0
    unsigned int slot = __umulhi(pat * 2654435761u, HS);
    for (;;) {
        const unsigned int old = atomicCAS(h + slot, HEMPTY, pat);
        if (old == HEMPTY) { u++; break; }
        if (old == pat) break;
        if (++slot == HS) slot = 0;
    }
}

// ---------------- K1: fused 2-column stats + hash + MLP ----------------
// 512 threads, 3 blocks/CU (LDS ~50.5 KB), rows walked in class-sorted order.
__launch_bounds__(512, 6)
__global__ void fused2_kernel(const float* __restrict__ X,
                              const int* __restrict__ perm,
                              const int* __restrict__ prefix,
                              const float* __restrict__ w1,
                              const float* __restrict__ b1,
                              const float* __restrict__ w2,
                              const float* __restrict__ b2,
                              float* __restrict__ out) {
    __shared__ unsigned int hash[2][HS];       // 48 KB
    __shared__ float red[8][32];
    __shared__ float stats_s[2][6];
    __shared__ float h_s[64];

    const int w  = blockIdx.x;                  // [0, 4096)
    const int g2 = (w & 7) * 512 + (w >> 3);    // XCD swizzle: adjacent col-pairs share an XCD
    const int b  = g2 >> 8;
    const int f0 = (g2 & 255) << 1;
    const int tid = threadIdx.x;
    const int lane = tid & 63, wv = tid >> 6;

    {   // init both hashes: 2*6144 uints = 3072 uint4 = 6/thread
        uint4* hp = (uint4*)&hash[0][0];
        #pragma unroll
        for (int i = 0; i < 6; i++)
            hp[tid + i * 512] = make_uint4(HEMPTY, HEMPTY, HEMPTY, HEMPTY);
    }
    int Pc[NC + 1];                              // block-uniform -> SGPRs
    #pragma unroll
    for (int i = 0; i < NC + 1; i++) Pc[i] = prefix[b * (NC + 1) + i];
    __syncthreads();

    const int*   pp = perm + b * NS;
    const float* Xb = X + (size_t)b * NS * NF + f0;

    // wave wv owns sorted positions [wv*512, wv*512+512); lane p's are consecutive per k
    int rows[8];
    #pragma unroll
    for (int k = 0; k < 8; k++) rows[k] = pp[wv * 512 + k * 64 + lane];
    float2 xv[8];
    #pragma unroll
    for (int k = 0; k < 8; k++) xv[k] = *(const float2*)(Xb + (size_t)rows[k] * NF);

    float sum0 = 0.f, sq0 = 0.f, ab0 = 0.f, nn0 = 0.f, mx0 = 0.f;
    float sum1 = 0.f, sq1 = 0.f, ab1 = 0.f, nn1 = 0.f, mx1 = 0.f;
    float cs0[NC], cs1[NC];
    int u0 = 0, u1 = 0;
    #pragma unroll
    for (int c = 0; c < NC; c++) { cs0[c] = 0.f; cs1[c] = 0.f; }

    const int wbase = __builtin_amdgcn_readfirstlane(wv * 512);   // scalar wave base

    #pragma unroll
    for (int k = 0; k < 8; k++) {
        float x0 = xv[k].x, x1 = xv[k].y;
        if (x0 != x0) { nn0 += 1.f; x0 = 0.f; }
        if (x1 != x1) { nn1 += 1.f; x1 = 0.f; }
        sum0 += x0; sq0 = fmaf(x0, x0, sq0); ab0 += fabsf(x0); mx0 = fmaxf(mx0, fabsf(x0));
        sum1 += x1; sq1 = fmaf(x1, x1, sq1); ab1 += fabsf(x1); mx1 = fmaxf(mx1, fabsf(x1));

        // class-segment accumulate: wave covers sorted positions [lo_s, lo_s+63]
        const int lo_s = wbase + k * 64;
        const int p = lo_s + lane;
        #pragma unroll
        for (int c = 0; c < NC; c++) {
            if (Pc[c] <= lo_s + 63 && Pc[c + 1] > lo_s) {        // scalar intersect test
                if (Pc[c] <= lo_s && Pc[c + 1] > lo_s + 63) {    // fully inside class c
                    cs0[c] += x0; cs1[c] += x1;
                } else {
                    const bool in = (p >= Pc[c]) && (p < Pc[c + 1]);
                    cs0[c] += in ? x0 : 0.f;
                    cs1[c] += in ? x1 : 0.f;
                }
            }
        }
        hash_insert(hash[0], x0, u0);
        hash_insert(hash[1], x1, u1);
    }

    // per-wave reductions -> LDS
    {
        float a[32];
        a[0]=sum0; a[1]=sq0; a[2]=ab0; a[3]=nn0; a[4]=mx0; a[5]=(float)u0;
        a[16]=sum1; a[17]=sq1; a[18]=ab1; a[19]=nn1; a[20]=mx1; a[21]=(float)u1;
        #pragma unroll
        for (int c = 0; c < NC; c++) { a[6+c]=cs0[c]; a[22+c]=cs1[c]; }
        #pragma unroll
        for (int j = 0; j < 32; j++) {
            const float r = (j==4 || j==20) ? wred_max(a[j]) : wred_add(a[j]);
            if (lane == 0) red[wv][j] = r;
        }
    }
    __syncthreads();

    if (tid == 0) {
        #pragma unroll
        for (int col = 0; col < 2; col++) {
            float t[16];
            #pragma unroll
            for (int j = 0; j < 16; j++) t[j] = red[0][col*16+j];
            #pragma unroll
            for (int wi = 1; wi < 8; wi++) {
                #pragma unroll
                for (int j = 0; j < 16; j++) {
                    if (j == 4) t[j] = fmaxf(t[j], red[wi][col*16+j]);
                    else        t[j] += red[wi][col*16+j];
                }
            }
            const float invS = 1.f / (float)NS;
            const float gmean    = t[0] * invS;
            const float variance = fmaxf(t[1] * invS - gmean * gmean, 0.f);
            const float mean_abs = t[2] * invS;
            const float missing  = t[3] * invS;
            const float max_abs  = t[4];
            const float n_unique = t[5];
            float between = 0.f;
            #pragma unroll
            for (int c = 0; c < NC; c++) {
                const float cnt = (float)(Pc[c + 1] - Pc[c]);
                const float cm  = t[6 + c] / fmaxf(cnt, 1.f);
                const float d   = cm - gmean;
                between += cnt * d * d;
            }
            between *= invS;
            const float target = between / fmaxf(variance, 1e-6f);
            float st[6] = { target, missing, n_unique * invS, variance, mean_abs, max_abs };
            #pragma unroll
            for (int i = 0; i < 6; i++) {
                float v = st[i];
                if (!(fabsf(v) < INFINITY)) v = 0.f;             // nan_to_num
                stats_s[col][i] = v;
            }
        }
    }
    __syncthreads();

    // MLP epilogue per column: 6 -> 64 (exact GELU) -> 128
    #pragma unroll
    for (int col = 0; col < 2; col++) {
        if (tid < 64) {
            float z = b1[tid];
            #pragma unroll
            for (int i = 0; i < 6; i++) z = fmaf(stats_s[col][i], w1[i * 64 + tid], z);
            h_s[tid] = 0.5f * z * (1.f + erff(z * 0.70710678118654752440f));
        }
        __syncthreads();
        if (tid < 128) {
            float o = b2[tid];
            #pragma unroll
            for (int j = 0; j < 64; j++) o = fmaf(h_s[j], w2[j * 128 + tid], o);
            out[((size_t)(b * NF + f0 + col)) * 128 + tid] = o;
        }
        __syncthreads();
    }
}

extern "C" void kernel_launch(void* const* d_in, const int* in_sizes, int n_in,
                              void* d_out, int out_size, void* d_ws, size_t ws_size,
                              hipStream_t stream) {
    const float* X  = (const float*)d_in[0];
    const int*   y  = (const int*)d_in[1];
    const float* w1 = (const float*)d_in[2];
    const float* b1 = (const float*)d_in[3];
    const float* w2 = (const float*)d_in[4];
    const float* b2 = (const float*)d_in[5];
    float* out   = (float*)d_out;
    int* perm    = (int*)d_ws;
    int* prefix  = (int*)((char*)d_ws + PERM_BYTES);

    sort_rows_kernel<<<NB, 256, 0, stream>>>(y, perm, prefix);
    fused2_kernel<<<NB * NF / 2, 512, 0, stream>>>(X, perm, prefix, w1, b1, w2, b2, out);
}